// Round 6
// baseline (23.590 us; speedup 1.0000x reference)
//
#include <hip/hip_runtime.h>
#include <hip/hip_bf16.h>

#define BS  32
#define J   4
#define L   512
#define D   768
#define K   4
#define OUT 256
// entity e = b*16 + j*4 + k (reference reshape order); sentence = e>>2 (128)

typedef float f4 __attribute__((ext_vector_type(4)));

// ---------------- Kernel A: ragged span mean-pool (quarter-span blocks) -----
// 2048 blocks = entity e (512) x quarter q (4); 128 threads = 2 waves.
// Quarter q owns tokens l in [start,end) with (l-start) % 4 == q; wave w takes
// every other one (stride 8). Scales by 1/count, writes partial row to
// ws[sent][q][k][768]; GEMM sums the four quarters (exact by linearity).
__global__ __launch_bounds__(128) void pool_kernel(
    const float* __restrict__ Z,    // [BS,J,L,D]
    const int*   __restrict__ sep,  // [BS,J,K]
    float*       __restrict__ ws)   // [128][4][4][768]
{
    const int blk  = blockIdx.x;      // 0..2047
    const int e    = blk >> 2, q = blk & 3;
    const int sent = e >> 2,  k = e & 3;
    const int end   = sep[sent * K + k];
    const int prev  = (k == 0) ? 0 : sep[sent * K + k - 1];
    const int start = prev + 1;
    const float inv = 1.0f / (float)(end - start);

    const int w    = threadIdx.x >> 6;   // 0..1
    const int lane = threadIdx.x & 63;
    const float* zbase = Z + (size_t)sent * L * D + lane * 4;

    f4 a0={0,0,0,0}, a1={0,0,0,0}, a2={0,0,0,0};
    f4 c0={0,0,0,0}, c1={0,0,0,0}, c2={0,0,0,0};

    int l = start + q + 4 * w;                 // this wave: stride 8
    for (; l + 8 < end; l += 16) {             // 2 tokens/iter: 6 loads in flight
        const float* r0 = zbase + (size_t)l * D;
        const float* r1 = zbase + (size_t)(l + 8) * D;
        a0 += *(const f4*)(r0);       a1 += *(const f4*)(r0 + 256);
        a2 += *(const f4*)(r0 + 512);
        c0 += *(const f4*)(r1);       c1 += *(const f4*)(r1 + 256);
        c2 += *(const f4*)(r1 + 512);
    }
    if (l < end) {
        const float* r0 = zbase + (size_t)l * D;
        a0 += *(const f4*)(r0);       a1 += *(const f4*)(r0 + 256);
        a2 += *(const f4*)(r0 + 512);
    }
    a0 += c0; a1 += c1; a2 += c2;

    __shared__ float part[2][D];               // 6 KB
    *(f4*)&part[w][lane*4]       = a0;
    *(f4*)&part[w][lane*4 + 256] = a1;
    *(f4*)&part[w][lane*4 + 512] = a2;
    __syncthreads();

    float* dst = ws + ((size_t)(sent * 4 + q) * K + k) * D;
    for (int i = threadIdx.x; i < 192; i += 128) {   // 192 f4 = 768 floats
        f4 s = *(const f4*)&part[0][i*4] + *(const f4*)&part[1][i*4];
        s *= inv;
        *(f4*)&dst[i*4] = s;
    }
}

// ---------------- Kernel B: [512,768] @ [768,256] + bias --------------------
// 512 blocks = (sentence g, col-quarter cq); 512 threads = 8 waves (16 w/CU).
// Stage: p[e][d] = sum_q ws[g][q][e][d]. Compute: wave w owns 96-d chunk;
// lane = (dg in [0,4), cl in [0,16)): d = w*96 + dg + 4i (consecutive d across
// dg -> conflict-free LDS broadcast), cl picks float4 of cols -> 16B coalesced
// W loads, 16 FMA/load, unroll 8. 32-slice LDS reduce, + bias, store.
__global__ __launch_bounds__(512) void gemm_kernel(
    const float* __restrict__ ws,   // [128][4][4][768]
    const float* __restrict__ W,    // [D, OUT]
    const float* __restrict__ bias, // [OUT]
    float*       __restrict__ out)  // [512, OUT]
{
    const int g  = blockIdx.x >> 2;
    const int cq = blockIdx.x & 3;

    __shared__ float p[K * D];                 // 12 KB
    __shared__ float red[32][K][64];           // 32 KB
    {
        const f4* a = (const f4*)(ws + (size_t)g * 4 * K * D);
        for (int i = threadIdx.x; i < (K * D) / 4; i += 512) {   // 768 f4
            f4 v = a[i] + a[i + 768] + a[i + 2 * 768] + a[i + 3 * 768];
            *(f4*)&p[i * 4] = v;
        }
    }
    __syncthreads();

    const int w    = threadIdx.x >> 6;        // 0..7: d-chunk of 96
    const int lane = threadIdx.x & 63;
    const int dg   = lane >> 4;
    const int cl   = lane & 15;
    const int colbase = cq * 64 + cl * 4;
    const int dbase   = w * 96 + dg;

    f4 acc0={0,0,0,0}, acc1={0,0,0,0}, acc2={0,0,0,0}, acc3={0,0,0,0};
    #pragma unroll 8
    for (int i = 0; i < 24; ++i) {
        const int d = dbase + 4 * i;
        f4 wv = *(const f4*)&W[(size_t)d * OUT + colbase];   // 16B coalesced
        acc0 += p[0 * D + d] * wv;             // LDS broadcast within cl group
        acc1 += p[1 * D + d] * wv;
        acc2 += p[2 * D + d] * wv;
        acc3 += p[3 * D + d] * wv;
    }

    const int r = w * 4 + dg;                  // 0..31
    *(f4*)&red[r][0][cl * 4] = acc0;
    *(f4*)&red[r][1][cl * 4] = acc1;
    *(f4*)&red[r][2][cl * 4] = acc2;
    *(f4*)&red[r][3][cl * 4] = acc3;
    __syncthreads();

    if (threadIdx.x < 256) {
        const int e2  = threadIdx.x >> 6;      // entity
        const int col = threadIdx.x & 63;
        float s = bias[cq * 64 + col];
        #pragma unroll
        for (int rr = 0; rr < 32; ++rr) s += red[rr][e2][col];
        out[(size_t)(g * K + e2) * OUT + cq * 64 + col] = s;
    }
}

extern "C" void kernel_launch(void* const* d_in, const int* in_sizes, int n_in,
                              void* d_out, int out_size, void* d_ws, size_t ws_size,
                              hipStream_t stream) {
    const float* Z    = (const float*)d_in[0];
    const int*   sep  = (const int*)d_in[1];
    const float* W    = (const float*)d_in[2];
    const float* bias = (const float*)d_in[3];
    float*       out  = (float*)d_out;
    float*       ws   = (float*)d_ws;          // 128*4*4*768*4 = 6 MB scratch

    pool_kernel<<<4 * BS * J * K, 128, 0, stream>>>(Z, sep, ws);
    gemm_kernel<<<BS * J * K, 512, 0, stream>>>(ws, W, bias, out);
}